// Round 3
// baseline (624.209 us; speedup 1.0000x reference)
//
#include <hip/hip_runtime.h>

#define BB 16
#define CC 64
#define NN 65536
#define NBV 4
#define NPART 512              // per-batch wave partials: 128 blocks x 4 waves
#define BP (BB * NPART)

// ws layout (fp32 elems): score B*N | bval 2*BP | bidx 2*BP (int) | wpart BP*64 | sspart BP
//
// Structure change vs round-0 baseline: d2 is LANE-LOCAL (lane owns 2 pixels, loops all 64
// channels) -> zero __syncthreads in the hot loop, every wave independent and identical.
// Channel values are held in regs (float2 xv[64], fully unrolled) so the acc pass re-uses
// them with no second fetch. 64 independent dwordx2 loads/wave are batched by the compiler
// -> ~16KB in flight per wave continuously (vs bursty barrier-coupled groups before).

// Initial argmax over score_init + zero selectedPos. 128 blocks/batch x 512 px.
// Tie rule: larger value wins; equal -> smaller index (np.argmax = first max).
__global__ __launch_bounds__(256)
void k_argmax1(const float* __restrict__ sc_in,
               float* __restrict__ bval, int* __restrict__ bidx,
               float* __restrict__ sel_out) {
    int b = blockIdx.y, blk = blockIdx.x, tid = threadIdx.x;
    int lane = tid & 63, wv = tid >> 6;
    int n0 = blk * 512 + tid * 2;
    const float* s = sc_in + (size_t)b * NN;
    float v0 = s[n0], v1 = s[n0 + 1];
    float v = v0; int vi = n0;
    if (v1 > v) { v = v1; vi = n0 + 1; }      // ascending within thread; strict > = first max
    sel_out[(size_t)b * NN + n0] = 0.f;
    sel_out[(size_t)b * NN + n0 + 1] = 0.f;
    #pragma unroll
    for (int off = 32; off >= 1; off >>= 1) {
        float ov = __shfl_down(v, off, 64); int oi = __shfl_down(vi, off, 64);
        if (ov > v || (ov == v && oi < vi)) { v = ov; vi = oi; }
    }
    if (lane == 0) { bval[b * NPART + blk * 4 + wv] = v; bidx[b * NPART + blk * 4 + wv] = vi; }
}

// Main per-iteration kernel. grid=(128,B), 256 thr = 4 independent waves.
// Wave wv owns pixels [blk*512 + wv*128, +128), lane owns 2 consecutive pixels.
// Prologue: stage-2 argmax over 512 partials (LDS tree) + raw gather (the only barriers).
// Hot path: 64x global_load_dwordx2 (512B/wave/instr, all independent) -> lane-local d2
// -> sim -> sim/score I/O -> acc pass from registers. Epilogue: per-wave butterflies.
__global__ __launch_bounds__(256, 2)
void k_iter(const float* __restrict__ x, const float* __restrict__ score_in,
            float* __restrict__ score_out,
            float* __restrict__ bval, int* __restrict__ bidx,
            float* __restrict__ wpart, float* __restrict__ sspart,
            float* __restrict__ sim_out, int iter) {
    int b = blockIdx.y, blk = blockIdx.x, tid = threadIdx.x;
    int lane = tid & 63, wv = tid >> 6;
    __shared__ float sv[256]; __shared__ int si[256];
    __shared__ float raw_s[64];

    int rb = (iter & 1) * BP, wb = ((iter & 1) ^ 1) * BP;

    // stage-2 argmax over NPART=512 partials
    {
        const float* bv = bval + rb + b * NPART;
        const int*  bi = bidx + rb + b * NPART;
        float v = bv[tid]; int vi = bi[tid];
        float v2 = bv[tid + 256]; int vi2 = bi[tid + 256];
        if (v2 > v || (v2 == v && vi2 < vi)) { v = v2; vi = vi2; }
        sv[tid] = v; si[tid] = vi;
        __syncthreads();
        for (int st = 128; st > 0; st >>= 1) {
            if (tid < st) {
                float ov = sv[tid + st]; int oi = si[tid + st];
                if (ov > sv[tid] || (ov == sv[tid] && oi < si[tid])) { sv[tid] = ov; si[tid] = oi; }
            }
            __syncthreads();
        }
    }
    int ind = si[0];                            // valid: tree loop ends with a barrier
    if (tid < 64) raw_s[tid] = x[((size_t)(b * 64 + tid)) * NN + ind];
    __syncthreads();

    int p = blk * 4 + wv;
    int n0 = blk * 512 + wv * 128 + lane * 2;
    const float* xb = x + (size_t)b * 64 * NN + n0;
    const size_t sb = (size_t)b * NN;
    const bool upd = (iter < 3);

    float2 sc = make_float2(0.f, 0.f);
    if (upd) sc = *(const float2*)(score_in + sb + n0);

    // batch all 64 channel loads (independent -> deep MLP), then lane-local d2
    float2 xv[64];
    #pragma unroll
    for (int c = 0; c < 64; c++) xv[c] = *(const float2*)(xb + (size_t)c * NN);
    float d2x = 0.f, d2y = 0.f;
    #pragma unroll
    for (int c = 0; c < 64; c++) {
        float r = raw_s[c];
        float dx = xv[c].x - r, dy = xv[c].y - r;
        d2x = fmaf(dx, dx, d2x); d2y = fmaf(dy, dy, d2y);
    }

    float simx = expf(-sqrtf(fmaxf(d2x, 1e-12f)) * 0.05f);
    float simy = expf(-sqrtf(fmaxf(d2y, 1e-12f)) * 0.05f);
    *(float2*)(sim_out + ((size_t)(b * NBV + iter)) * NN + n0) = make_float2(simx, simy);

    float ss = simx + simy;
    float smax = -1e30f; int smaxi = 0x7fffffff;
    if (upd) {
        float ncx = sc.x * (1.f - simx), ncy = sc.y * (1.f - simy);
        *(float2*)(score_out + sb + n0) = make_float2(ncx, ncy);
        smax = ncx; smaxi = n0;                 // ascending; strict > = first max
        if (ncy > smax) { smax = ncy; smaxi = n0 + 1; }
    }

    // acc pass straight from registers (no re-fetch)
    float accl[64];
    #pragma unroll
    for (int c = 0; c < 64; c++) accl[c] = fmaf(simx, xv[c].x, simy * xv[c].y);

    // epilogue: per-wave cross-lane reductions (no barriers)
    #pragma unroll
    for (int c = 0; c < 64; c++) {
        float v = accl[c];
        #pragma unroll
        for (int off = 32; off >= 1; off >>= 1) v += __shfl_down(v, off, 64);
        if (lane == 0) wpart[((size_t)b * NPART + p) * 64 + c] = v;
    }
    #pragma unroll
    for (int off = 32; off >= 1; off >>= 1) ss += __shfl_down(ss, off, 64);
    if (lane == 0) sspart[b * NPART + p] = ss;
    if (upd) {
        #pragma unroll
        for (int off = 32; off >= 1; off >>= 1) {
            float ov = __shfl_down(smax, off, 64); int oi = __shfl_down(smaxi, off, 64);
            if (ov > smax || (ov == smax && oi < smaxi)) { smax = ov; smaxi = oi; }
        }
        if (lane == 0) { bval[wb + b * NPART + p] = smax; bidx[wb + b * NPART + p] = smaxi; }
    }
}

// Reduce 512 wave-partials per batch. grid=(B), 256 thr: thread (c=tid&63, q=tid>>6)
// sums a contiguous 128-chunk of partials for channel c; LDS combines.
__global__ __launch_bounds__(256)
void k_fin(const float* __restrict__ wpart, const float* __restrict__ sspart,
           float* __restrict__ vec_out, int iter) {
    int b = blockIdx.x, tid = threadIdx.x;
    int c = tid & 63, q = tid >> 6;
    __shared__ float lw[4][64];
    __shared__ float lss[256];
    lss[tid] = sspart[b * NPART + 2 * tid] + sspart[b * NPART + 2 * tid + 1];
    float w = 0.f;
    for (int i = 0; i < 128; i++) {
        int pp = q * 128 + i;
        w += wpart[((size_t)b * NPART + pp) * 64 + c];
    }
    lw[q][c] = w;
    __syncthreads();
    for (int st = 128; st > 0; st >>= 1) {
        if (tid < st) lss[tid] += lss[tid + st];
        __syncthreads();
    }
    if (tid < 64) {
        float tot = (lw[0][tid] + lw[1][tid]) + (lw[2][tid] + lw[3][tid]);
        vec_out[(b * NBV + iter) * 64 + tid] = tot / lss[0];
    }
}

extern "C" void kernel_launch(void* const* d_in, const int* in_sizes, int n_in,
                              void* d_out, int out_size, void* d_ws, size_t ws_size,
                              hipStream_t stream) {
    const float* x = (const float*)d_in[0];           // [B,C,H,W] fp32
    const float* sc_in = (const float*)d_in[1];       // [B,N] fp32
    float* out = (float*)d_out;                       // fp32 outputs
    float* vec_out = out;                             // B*4*C
    float* sim_out = vec_out + (size_t)BB * NBV * CC; // B*4*N
    float* sel_out = sim_out + (size_t)BB * NBV * NN; // B*N

    float* ws = (float*)d_ws;
    float* score = ws;                                // B*N
    float* bval = ws + (size_t)BB * NN;               // 2*BP
    int* bidx = (int*)(bval + 2 * BP);                // 2*BP
    float* wpart = bval + 4 * BP;                     // BP*64
    float* sspart = wpart + (size_t)BP * 64;          // BP

    k_argmax1<<<dim3(128, BB), 256, 0, stream>>>(sc_in, bval, bidx, sel_out);
    for (int it = 0; it < NBV; it++) {
        const float* s_in = (it == 0) ? sc_in : score;
        k_iter<<<dim3(128, BB), 256, 0, stream>>>(x, s_in, score, bval, bidx,
                                                  wpart, sspart, sim_out, it);
        k_fin<<<dim3(BB), 256, 0, stream>>>(wpart, sspart, vec_out, it);
    }
}